// Round 6
// baseline (726.536 us; speedup 1.0000x reference)
//
#include <hip/hip_runtime.h>
#include <cstdint>
#include <cstddef>

// Problem constants (fixed by the reference setup)
#define N_NODES 50000
#define N_PAD   50048   // 391 * 128, so GEMM A-tiles never go OOB
#define N_EDGES 800000
#define F_INPUT 128
#define DIM 256
#define NLAYERS 3
#define NGRAPHS 512
#define NBH 64          // histogram/fill blocks
#define EPB 12500       // edges per histogram block (64*12500 = 800000)
#define NGB 391         // GEMM m-blocks (N_PAD/128)

typedef __bf16 bf16_t;
typedef bf16_t bf16x8 __attribute__((ext_vector_type(8)));
typedef float f32x4 __attribute__((ext_vector_type(4)));

__device__ __forceinline__ float bf2f(unsigned short u) {
    union { unsigned u32; float f; } x; x.u32 = ((unsigned)u) << 16; return x.f;
}
__device__ __forceinline__ unsigned short f2bf(float f) {
    union { float f; unsigned u; } x; x.f = f;
    unsigned r = (x.u + 0x7fffu + ((x.u >> 16) & 1u)) >> 16;
    return (unsigned short)r;
}

__device__ __forceinline__ void gl_lds16(const unsigned short* g, unsigned short* l) {
    __builtin_amdgcn_global_load_lds(
        (const __attribute__((address_space(1))) void*)g,
        (__attribute__((address_space(3))) void*)l, 16, 0, 0);
}

// ---- merged prep: weight hi/lo split+transpose AND x f32->bf16 (needs 6250 blocks)
__global__ void k_prep(const float* __restrict__ W_enc, const float* __restrict__ W1,
                       const float* __restrict__ W2, const float* __restrict__ x,
                       unsigned short* __restrict__ wench, unsigned short* __restrict__ wencl,
                       unsigned short* __restrict__ w1h, unsigned short* __restrict__ w1l,
                       unsigned short* __restrict__ w2h, unsigned short* __restrict__ w2l,
                       unsigned short* __restrict__ xb) {
    int idx = blockIdx.x * 256 + threadIdx.x;
    if (idx < 32768) {                       // W_enc [128][256] -> [256][128] hi/lo
        float w = W_enc[idx];
        int k = idx >> 8, n = idx & 255;
        unsigned short h = f2bf(w), lo = f2bf(w - bf2f(h));
        wench[n * 128 + k] = h; wencl[n * 128 + k] = lo;
    } else if (idx < 32768 + 196608) {       // W1 [3][256][256] -> [3][256][256]^T
        int j = idx - 32768;
        int l = j >> 16, r = j & 65535, k = r >> 8, n = r & 255;
        float w = W1[j];
        unsigned short h = f2bf(w), lo = f2bf(w - bf2f(h));
        w1h[l * 65536 + n * 256 + k] = h; w1l[l * 65536 + n * 256 + k] = lo;
    } else if (idx < 32768 + 2 * 196608) {   // W2
        int j = idx - 32768 - 196608;
        int l = j >> 16, r = j & 65535, k = r >> 8, n = r & 255;
        float w = W2[j];
        unsigned short h = f2bf(w), lo = f2bf(w - bf2f(h));
        w2h[l * 65536 + n * 256 + k] = h; w2l[l * 65536 + n * 256 + k] = lo;
    }
    if (idx < (N_NODES * F_INPUT) / 4) {     // x -> bf16, 4 at a time
        float4 v = reinterpret_cast<const float4*>(x)[idx];
        ushort4 o;
        o.x = f2bf(v.x); o.y = f2bf(v.y); o.z = f2bf(v.z); o.w = f2bf(v.w);
        reinterpret_cast<ushort4*>(xb)[idx] = o;
    }
}

// ---- per-block LDS histogram of dst (packed 2x16-bit, 2 node-range passes)
__global__ __launch_bounds__(512) void k_count(const int* __restrict__ dst,
                                               unsigned* __restrict__ slab) {
    __shared__ unsigned bins[16384];
    int b = blockIdx.x, t = threadIdx.x;
    int e0 = b * EPB, e1 = e0 + EPB;
    for (int pass = 0; pass < 2; ++pass) {
        int lo = pass << 15;
        int words = pass ? 8616 : 16384;
        for (int w = t; w < 16384; w += 512) bins[w] = 0;
        __syncthreads();
        for (int e = e0 + t; e < e1; e += 512) {
            int r = dst[e] - lo;
            if ((unsigned)r < 32768u)
                atomicAdd(&bins[r >> 1], 1u << ((r & 1) * 16));
        }
        __syncthreads();
        unsigned* out = slab + b * 25000 + (pass ? 16384 : 0);
        for (int w = t; w < words; w += 512) out[w] = bins[w];
        __syncthreads();
    }
}

// ---- reduce count slabs -> deg; graph boundaries from sorted batch -> gstart
__global__ void k_degred(const unsigned* __restrict__ slab, const int* __restrict__ batch,
                         int* __restrict__ deg, int* __restrict__ gstart) {
    int i = blockIdx.x * 256 + threadIdx.x;
    if (i < 25000) {
        unsigned s = 0;
#pragma unroll 8
        for (int b = 0; b < NBH; ++b) s += slab[b * 25000 + i];
        deg[2 * i] = s & 0xffff;
        deg[2 * i + 1] = s >> 16;
    }
    if (i < N_NODES) {
        int bt = batch[i];
        int pb = (i == 0) ? -1 : batch[i - 1];
        if (bt != pb)
            for (int g = pb + 1; g <= bt; ++g) gstart[g] = i;
        if (i == N_NODES - 1)
            for (int g = bt + 1; g <= NGRAPHS; ++g) gstart[g] = N_NODES;
    }
}

// ---- scan step 1: per-block inclusive scan of deg padded to multiple of 4
__global__ void k_scan1(const int* __restrict__ deg, int* __restrict__ rp1,
                        int* __restrict__ bsum) {
    __shared__ int s[256];
    int t = threadIdx.x, b = blockIdx.x, i = b * 256 + t;
    int d = (i < N_NODES) ? deg[i] : 0;
    int v = (d + 3) & ~3;    // pad each node's edge list to multiple of 4
    s[t] = v; __syncthreads();
    for (int off = 1; off < 256; off <<= 1) {
        int x = (t >= off) ? s[t - off] : 0;
        __syncthreads(); s[t] += x; __syncthreads();
    }
    if (i < N_NODES) rp1[i] = s[t];
    if (t == 255) bsum[b] = s[255];
}

// ---- scan step 2: exclusive scan of block sums
__global__ void k_scan2(const int* __restrict__ bsum, int* __restrict__ boff, int nb) {
    __shared__ int s[256];
    int t = threadIdx.x;
    int v = (t < nb) ? bsum[t] : 0;
    s[t] = v; __syncthreads();
    for (int off = 1; off < 256; off <<= 1) {
        int x = (t >= off) ? s[t - off] : 0;
        __syncthreads(); s[t] += x; __syncthreads();
    }
    if (t < nb) boff[t] = s[t] - v;
}

// ---- scan step 3: add block offsets; finalize row_ptr[0]
__global__ void k_scan3(int* __restrict__ row_ptr, const int* __restrict__ boff) {
    int t = threadIdx.x, b = blockIdx.x, i = b * 256 + t;
    if (i < N_NODES) row_ptr[1 + i] += boff[b];
    if (i == 0) row_ptr[0] = 0;
}

// ---- per-(block,node) exclusive bases from count slabs; write pad edges (src = N_NODES)
__global__ void k_base(const unsigned* __restrict__ slab, const int* __restrict__ row_ptr,
                       int* __restrict__ base, int* __restrict__ csr_src) {
    int n = blockIdx.x * 256 + threadIdx.x;
    if (n >= N_NODES) return;
    int w = n >> 1, sh = (n & 1) * 16;
    int cur = row_ptr[n];
    int start = cur;
#pragma unroll 4
    for (int b = 0; b < NBH; ++b) {
        base[b * N_NODES + n] = cur;
        cur += (slab[b * 25000 + w] >> sh) & 0xffff;
    }
    int dg = cur - start;
    int padded = (dg + 3) & ~3;
    for (int p = dg; p < padded; ++p) csr_src[start + p] = N_NODES;
}

// ---- CSR fill with LDS cursors (no global atomics)
__global__ __launch_bounds__(512) void k_fill2(const int* __restrict__ src,
                                               const int* __restrict__ dst,
                                               const int* __restrict__ base,
                                               int* __restrict__ csr_src) {
    __shared__ unsigned bins[16384];
    int b = blockIdx.x, t = threadIdx.x;
    int e0 = b * EPB, e1 = e0 + EPB;
    for (int pass = 0; pass < 2; ++pass) {
        int lo = pass << 15;
        for (int w = t; w < 16384; w += 512) bins[w] = 0;
        __syncthreads();
        for (int e = e0 + t; e < e1; e += 512) {
            int d = dst[e];
            int r = d - lo;
            if ((unsigned)r < 32768u) {
                int sh = (r & 1) * 16;
                unsigned old = atomicAdd(&bins[r >> 1], 1u << sh);
                int local = (old >> sh) & 0xffff;
                csr_src[base[b * N_NODES + d] + local] = src[e];
            }
        }
        __syncthreads();
    }
}

// ---- aggregation, optionally fused with BN-affine+relu of the input
template <bool BN>
__global__ void k_agg(const unsigned short* __restrict__ zin, const int* __restrict__ row_ptr,
                      const int* __restrict__ csr_src,
                      const float* __restrict__ Ap, const float* __restrict__ Bp,
                      unsigned short* __restrict__ z0) {
    int wid = threadIdx.x >> 6, lane = threadIdx.x & 63;
    int half = lane >> 5, cl = lane & 31;
    int node = blockIdx.x * 8 + wid * 2 + half;   // grid = 6250
    const uint4* hp = reinterpret_cast<const uint4*>(zin);
    float Av[8], Bv[8];
    if (BN) {
        float4 a0 = *(const float4*)(Ap + cl * 8), a1 = *(const float4*)(Ap + cl * 8 + 4);
        float4 b0 = *(const float4*)(Bp + cl * 8), b1 = *(const float4*)(Bp + cl * 8 + 4);
        Av[0] = a0.x; Av[1] = a0.y; Av[2] = a0.z; Av[3] = a0.w;
        Av[4] = a1.x; Av[5] = a1.y; Av[6] = a1.z; Av[7] = a1.w;
        Bv[0] = b0.x; Bv[1] = b0.y; Bv[2] = b0.z; Bv[3] = b0.w;
        Bv[4] = b1.x; Bv[5] = b1.y; Bv[6] = b1.z; Bv[7] = b1.w;
    }
    uint4 own = hp[(size_t)node * 32 + cl];
    const unsigned short* op = (const unsigned short*)&own;
    float a[8];
#pragma unroll
    for (int i = 0; i < 8; ++i) {
        float z = bf2f(op[i]);
        a[i] = BN ? fmaxf(fmaf(Av[i], z, Bv[i]), 0.f) : z;
    }
    int e = row_ptr[node], end = row_ptr[node + 1];
    int4 nidx = {0, 0, 0, 0};
    if (e < end) nidx = *(const int4*)(csr_src + e);
    while (e < end) {
        int4 c = nidx;
        int en = e + 4;
        if (en < end) nidx = *(const int4*)(csr_src + en);
        uint4 v0 = hp[(size_t)c.x * 32 + cl];
        uint4 v1 = hp[(size_t)c.y * 32 + cl];
        uint4 v2 = hp[(size_t)c.z * 32 + cl];
        uint4 v3 = hp[(size_t)c.w * 32 + cl];
        e = en;
        const unsigned short* p0 = (const unsigned short*)&v0;
        const unsigned short* p1 = (const unsigned short*)&v1;
        const unsigned short* p2 = (const unsigned short*)&v2;
        const unsigned short* p3 = (const unsigned short*)&v3;
        if (BN) {
            float f0 = (c.x < N_NODES) ? 1.f : 0.f;
            float f1 = (c.y < N_NODES) ? 1.f : 0.f;
            float f2 = (c.z < N_NODES) ? 1.f : 0.f;
            float f3 = (c.w < N_NODES) ? 1.f : 0.f;
#pragma unroll
            for (int i = 0; i < 8; ++i) {
                float r0 = fmaxf(fmaf(Av[i], bf2f(p0[i]), Bv[i]), 0.f);
                float r1 = fmaxf(fmaf(Av[i], bf2f(p1[i]), Bv[i]), 0.f);
                float r2 = fmaxf(fmaf(Av[i], bf2f(p2[i]), Bv[i]), 0.f);
                float r3 = fmaxf(fmaf(Av[i], bf2f(p3[i]), Bv[i]), 0.f);
                a[i] += f0 * r0 + f1 * r1 + f2 * r2 + f3 * r3;
            }
        } else {
#pragma unroll
            for (int i = 0; i < 8; ++i)
                a[i] += (bf2f(p0[i]) + bf2f(p1[i])) + (bf2f(p2[i]) + bf2f(p3[i]));
        }
    }
    uint4 o;
    unsigned short* po = (unsigned short*)&o;
#pragma unroll
    for (int i = 0; i < 8; ++i) po[i] = f2bf(a[i]);
    reinterpret_cast<uint4*>(z0)[(size_t)node * 32 + cl] = o;
}

// ---- MFMA GEMM. A staged in LDS (read-once stream); B (weights, L2-resident ~512KB)
// loaded DIRECTLY global->VGPR as per-lane 16B fragments — no B LDS, no B staging
// instructions, B decoupled from the barrier drain. Optional fused column stats.
template <int K, bool RELU, bool STATS>
__global__ __launch_bounds__(256) void k_gemm(const unsigned short* __restrict__ A,
                                              const unsigned short* __restrict__ Whi,
                                              const unsigned short* __restrict__ Wlo,
                                              const float* __restrict__ bias,
                                              unsigned short* __restrict__ C,
                                              float* __restrict__ statsbuf, int M) {
    __shared__ __align__(16) unsigned short As[128 * 32];   // 8 KB
    __shared__ float st[2][2][128];
    const int tid = threadIdx.x;
    const int m0 = blockIdx.x * 128;
    const int n0 = blockIdx.y * 128;
    const int wid = tid >> 6, lane = tid & 63;
    const int wm = (wid & 1) * 64, wn = (wid >> 1) * 64;
    const int lm = lane & 15, q = lane >> 4;

    // per-lane byte offsets into Whi/Wlo for the 4 j-tiles (col-major K rows)
    unsigned boff[4];
#pragma unroll
    for (int j = 0; j < 4; ++j) {
        int col = n0 + wn + j * 16 + lm;
        boff[j] = (unsigned)(col * K + q * 8) * 2u;
    }

    f32x4 acc[4][4];
#pragma unroll
    for (int i = 0; i < 4; ++i)
#pragma unroll
        for (int j = 0; j < 4; ++j) acc[i][j] = (f32x4){0.f, 0.f, 0.f, 0.f};

    for (int k0 = 0; k0 < K; k0 += 32) {
        // stage A tile (128 rows x 32 k): 2 x 16B DMA per thread
#pragma unroll
        for (int hf = 0; hf < 2; ++hf) {
            int r = (tid >> 2) + hf * 64;
            gl_lds16(A + (size_t)(m0 + r) * K + k0 + (tid & 3) * 8,
                     &As[r * 32 + (tid & 3) * 8]);
        }
        __syncthreads();
        // B fragments: direct 16B global loads (L2-hit), k-chunk offset = 2*k0 bytes
        bf16x8 bh[4], bl[4], af[4];
#pragma unroll
        for (int j = 0; j < 4; ++j) {
            bh[j] = *reinterpret_cast<const bf16x8*>((const char*)Whi + boff[j] + (k0 << 1));
            bl[j] = *reinterpret_cast<const bf16x8*>((const char*)Wlo + boff[j] + (k0 << 1));
        }
#pragma unroll
        for (int i = 0; i < 4; ++i)
            af[i] = *reinterpret_cast<const bf16x8*>(&As[(wm + i * 16 + lm) * 32 + q * 8]);
#pragma unroll
        for (int i = 0; i < 4; ++i)
#pragma unroll
            for (int j = 0; j < 4; ++j) {
                acc[i][j] = __builtin_amdgcn_mfma_f32_16x16x32_bf16(af[i], bl[j], acc[i][j], 0, 0, 0);
                acc[i][j] = __builtin_amdgcn_mfma_f32_16x16x32_bf16(af[i], bh[j], acc[i][j], 0, 0, 0);
            }
        __syncthreads();
    }
    float bv[4];
#pragma unroll
    for (int j = 0; j < 4; ++j) bv[j] = bias[n0 + wn + j * 16 + lm];
#pragma unroll
    for (int j = 0; j < 4; ++j) {
        int col = n0 + wn + j * 16 + lm;
        float s = 0.f, s2 = 0.f;
#pragma unroll
        for (int i = 0; i < 4; ++i) {
            int row0 = m0 + wm + i * 16 + q * 4;
#pragma unroll
            for (int r = 0; r < 4; ++r) {
                int row = row0 + r;
                if (row < M) {
                    float v = acc[i][j][r] + bv[j];
                    if (STATS) { s += v; s2 = fmaf(v, v, s2); }
                    if (RELU) v = fmaxf(v, 0.f);
                    C[(size_t)row * DIM + col] = f2bf(v);
                }
            }
        }
        if (STATS) {
            s += __shfl_xor(s, 16); s += __shfl_xor(s, 32);
            s2 += __shfl_xor(s2, 16); s2 += __shfl_xor(s2, 32);
            if (q == 0) {
                st[0][wid & 1][wn + j * 16 + lm] = s;
                st[1][wid & 1][wn + j * 16 + lm] = s2;
            }
        }
    }
    if (STATS) {
        __syncthreads();
        if (tid < 256) {
            int sel = tid >> 7, cl2 = tid & 127;
            float v = st[sel][0][cl2] + st[sel][1][cl2];
            statsbuf[(size_t)(blockIdx.y * gridDim.x + blockIdx.x) * 256 + sel * 128 + cl2] = v;
        }
    }
}

// ---- stats reduce stage 1: 32 blocks x 512 thr, partial sums over slab chunks
__global__ __launch_bounds__(512) void k_statred1(const float* __restrict__ statsbuf,
                                                  float* __restrict__ spart) {
    int b = blockIdx.x, t = threadIdx.x;
    int is2 = t >> 8, c = t & 255;
    int by = c >> 7, cl = c & 127;
    int x0 = b * 13, x1 = x0 + 13;
    if (x1 > NGB) x1 = NGB;
    float s = 0.f;
    for (int bx = x0; bx < x1; ++bx)
        s += statsbuf[(size_t)(by * NGB + bx) * 256 + is2 * 128 + cl];
    spart[b * 512 + t] = s;
}

// ---- stats reduce stage 2: finalize BN affine  A=gamma*inv, B=beta-mean*A
__global__ void k_statred2(const float* __restrict__ spart, const float* __restrict__ gamma,
                           const float* __restrict__ beta, float* __restrict__ Ap,
                           float* __restrict__ Bp) {
    int c = threadIdx.x;   // 256
    float s = 0.f, s2 = 0.f;
#pragma unroll 8
    for (int b = 0; b < 32; ++b) {
        s += spart[b * 512 + c];
        s2 += spart[b * 512 + 256 + c];
    }
    float mean = s * (1.f / N_NODES);
    float var = s2 * (1.f / N_NODES) - mean * mean;
    float inv = rsqrtf(var + 1e-5f);
    float A = gamma[c] * inv;
    Ap[c] = A;
    Bp[c] = beta[c] - mean * A;
}

// ---- graph mean-pool of relu(A*z+B), unroll-4 independent accumulators
__global__ void k_pool(const unsigned short* __restrict__ z, const float* __restrict__ Ap,
                       const float* __restrict__ Bp, const int* __restrict__ gstart,
                       float* __restrict__ partl) {
    int g = blockIdx.x, sp = blockIdx.y, t = threadIdx.x;
    float A = Ap[t], B = Bp[t];
    int beg = gstart[g], c = gstart[g + 1] - beg;
    int chunk = (c + 3) >> 2;
    int r0 = beg + sp * chunk;
    int r1 = beg + c;
    int rlim = r0 + chunk;
    if (rlim < r1) r1 = rlim;
    float a0 = 0.f, a1 = 0.f, a2 = 0.f, a3 = 0.f;
    int r = r0;
    for (; r + 4 <= r1; r += 4) {
        float v0 = bf2f(z[(size_t)r * DIM + t]);
        float v1 = bf2f(z[(size_t)(r + 1) * DIM + t]);
        float v2 = bf2f(z[(size_t)(r + 2) * DIM + t]);
        float v3 = bf2f(z[(size_t)(r + 3) * DIM + t]);
        a0 += fmaxf(fmaf(A, v0, B), 0.f);
        a1 += fmaxf(fmaf(A, v1, B), 0.f);
        a2 += fmaxf(fmaf(A, v2, B), 0.f);
        a3 += fmaxf(fmaf(A, v3, B), 0.f);
    }
    for (; r < r1; ++r)
        a0 += fmaxf(fmaf(A, bf2f(z[(size_t)r * DIM + t]), B), 0.f);
    partl[(size_t)(g * 4 + sp) * 256 + t] = (a0 + a1) + (a2 + a3);
}

// ---- FC head: sums pool partials, divides by cnt, 2-layer MLP
__global__ __launch_bounds__(1024) void k_fc(const float* __restrict__ part,
                                             const int* __restrict__ gstart,
                                             const float* __restrict__ W1,
                                             const float* __restrict__ b1,
                                             const float* __restrict__ W2,
                                             const float* __restrict__ b2,
                                             float* __restrict__ out) {
    __shared__ float gs[DIM * NLAYERS];
    __shared__ float pt[8][128];
    __shared__ float red2[2];
    int g = blockIdx.x, t = threadIdx.x;
    float invc = 1.f / fmaxf((float)(gstart[g + 1] - gstart[g]), 1.f);
    for (int i = t; i < DIM * NLAYERS; i += 1024) {
        int l = i >> 8, c = i & 255;
        const float* pl = part + ((size_t)(l * NGRAPHS + g) * 4) * 256 + c;
        gs[i] = (pl[0] + pl[256] + pl[512] + pl[768]) * invc;
    }
    __syncthreads();
    int o = t & 127, kk = t >> 7;
    float acc = 0.f;
    const float* wp = W1 + (size_t)(kk * 96) * 128 + o;
#pragma unroll 4
    for (int k = 0; k < 96; ++k) acc = fmaf(gs[kk * 96 + k], wp[(size_t)k * 128], acc);
    pt[kk][o] = acc;
    __syncthreads();
    if (t < 128) {
        float v = b1[o];
#pragma unroll
        for (int p = 0; p < 8; ++p) v += pt[p][o];
        v = fmaxf(v, 0.f) * W2[o];
#pragma unroll
        for (int off = 32; off; off >>= 1) v += __shfl_down(v, off, 64);
        if ((t & 63) == 0) red2[t >> 6] = v;
    }
    __syncthreads();
    if (t == 0) out[g] = red2[0] + red2[1] + b2[0];
}

extern "C" void kernel_launch(void* const* d_in, const int* in_sizes, int n_in,
                              void* d_out, int out_size, void* d_ws, size_t ws_size,
                              hipStream_t stream) {
    const float* x = (const float*)d_in[0];
    const int* ei = (const int*)d_in[1];
    const int* batch = (const int*)d_in[2];
    const float* W_enc = (const float*)d_in[4];
    const float* b_enc = (const float*)d_in[5];
    const float* W1 = (const float*)d_in[6];
    const float* b1 = (const float*)d_in[7];
    const float* W2 = (const float*)d_in[8];
    const float* b2 = (const float*)d_in[9];
    const float* gamma = (const float*)d_in[10];
    const float* beta = (const float*)d_in[11];
    const float* Wfc1 = (const float*)d_in[12];
    const float* bfc1 = (const float*)d_in[13];
    const float* Wfc2 = (const float*)d_in[14];
    const float* bfc2 = (const float*)d_in[15];
    float* out = (float*)d_out;
    const int* srcp = ei;
    const int* dstp = ei + N_EDGES;

    // Workspace bump allocator (~110 MB)
    char* w = (char*)d_ws;
    auto alloc = [&](size_t b) -> char* {
        char* p = w;
        w += (b + 255) & ~(size_t)255;
        return p;
    };
    unsigned short* xb   = (unsigned short*)alloc((size_t)N_PAD * F_INPUT * 2);
    unsigned short* hbuf = (unsigned short*)alloc((size_t)N_PAD * DIM * 2);  // enc out; z0 for l>=1
    unsigned short* zA   = (unsigned short*)alloc((size_t)N_PAD * DIM * 2);  // z0@l0 / zbuf
    unsigned short* tbuf = (unsigned short*)alloc((size_t)N_PAD * DIM * 2);  // MLP mid; aliases basep
    unsigned short* wench = (unsigned short*)alloc(F_INPUT * DIM * 2);
    unsigned short* wencl = (unsigned short*)alloc(F_INPUT * DIM * 2);
    unsigned short* w1h = (unsigned short*)alloc((size_t)NLAYERS * DIM * DIM * 2);
    unsigned short* w1l = (unsigned short*)alloc((size_t)NLAYERS * DIM * DIM * 2);
    unsigned short* w2h = (unsigned short*)alloc((size_t)NLAYERS * DIM * DIM * 2);
    unsigned short* w2l = (unsigned short*)alloc((size_t)NLAYERS * DIM * DIM * 2);
    int* csr_src = (int*)alloc((size_t)(N_EDGES + 3 * N_NODES) * 4);
    int* row_ptr = (int*)alloc((size_t)(N_NODES + 1) * 4);
    unsigned* slab = (unsigned*)alloc((size_t)NBH * 25000 * 4);
    int* deg = (int*)alloc((size_t)N_NODES * 4);
    int* gstart = (int*)alloc((NGRAPHS + 1) * 4);
    int* bsum = (int*)alloc(256 * 4);
    int* boff = (int*)alloc(256 * 4);
    float* statsbuf = (float*)alloc((size_t)2 * NGB * 256 * 4);
    float* spart = (float*)alloc((size_t)32 * 512 * 4);
    float* Abn = (float*)alloc(256 * 4);
    float* Bbn = (float*)alloc(256 * 4);
    float* part = (float*)alloc((size_t)NLAYERS * NGRAPHS * 4 * 256 * 4);
    // basep (12.8 MB) aliases tbuf (25.6 MB): basep's lifetime (k_base..k_fill2) ends
    // before tbuf's first write (GEMM-1 of layer 0).
    int* basep = (int*)tbuf;

    // zero the dummy row (index N_NODES) of hbuf so pad edges add exact 0 in the plain agg
    hipMemsetAsync(hbuf + (size_t)N_NODES * DIM, 0, DIM * 2, stream);

    // prep: weights hi/lo + x->bf16 (6250 blocks: x-conversion bound)
    k_prep<<<6250, 256, 0, stream>>>(W_enc, W1, W2, x, wench, wencl, w1h, w1l, w2h, w2l, xb);

    // CSR build, atomic-free
    const int NB = (N_NODES + 255) / 256;  // 196
    k_count<<<NBH, 512, 0, stream>>>(dstp, slab);
    k_degred<<<NB, 256, 0, stream>>>(slab, batch, deg, gstart);
    k_scan1<<<NB, 256, 0, stream>>>(deg, row_ptr + 1, bsum);
    k_scan2<<<1, 256, 0, stream>>>(bsum, boff, NB);
    k_scan3<<<NB, 256, 0, stream>>>(row_ptr, boff);
    k_base<<<NB, 256, 0, stream>>>(slab, row_ptr, basep, csr_src);
    k_fill2<<<NBH, 512, 0, stream>>>(srcp, dstp, basep, csr_src);

    // encoder: h = x @ W_enc + b_enc
    dim3 ggrid(NGB, 2);
    k_gemm<F_INPUT, false, false><<<ggrid, 256, 0, stream>>>(xb, wench, wencl, b_enc, hbuf,
                                                             nullptr, N_NODES);

    dim3 pgrid(NGRAPHS, 4);
    for (int l = 0; l < NLAYERS; ++l) {
        const unsigned short* aggin = (l == 0) ? hbuf : zA;
        unsigned short* aggout = (l == 0) ? zA : hbuf;
        if (l == 0)
            k_agg<false><<<6250, 256, 0, stream>>>(aggin, row_ptr, csr_src, nullptr, nullptr, aggout);
        else
            k_agg<true><<<6250, 256, 0, stream>>>(aggin, row_ptr, csr_src, Abn, Bbn, aggout);
        k_gemm<DIM, true, false><<<ggrid, 256, 0, stream>>>(aggout, w1h + l * 65536, w1l + l * 65536,
                                                            b1 + l * DIM, tbuf, nullptr, N_NODES);
        k_gemm<DIM, false, true><<<ggrid, 256, 0, stream>>>(tbuf, w2h + l * 65536, w2l + l * 65536,
                                                            b2 + l * DIM, zA, statsbuf, N_NODES);
        k_statred1<<<32, 512, 0, stream>>>(statsbuf, spart);
        k_statred2<<<1, 256, 0, stream>>>(spart, gamma + l * DIM, beta + l * DIM, Abn, Bbn);
        k_pool<<<pgrid, 256, 0, stream>>>(zA, Abn, Bbn, gstart, part + (size_t)l * NGRAPHS * 4 * 256);
    }
    k_fc<<<NGRAPHS, 1024, 0, stream>>>(part, gstart, Wfc1, bfc1, Wfc2, bfc2, out);
}

// Round 7
// 627.317 us; speedup vs baseline: 1.1582x; 1.1582x over previous
//
#include <hip/hip_runtime.h>
#include <cstdint>
#include <cstddef>

// Problem constants (fixed by the reference setup)
#define N_NODES 50000
#define N_PAD   50048   // 391 * 128, so GEMM A-tiles never go OOB
#define N_EDGES 800000
#define F_INPUT 128
#define DIM 256
#define NLAYERS 3
#define NGRAPHS 512
#define NBH 64          // histogram/fill blocks
#define EPB 12500       // edges per histogram block (64*12500 = 800000)
#define NGB 391         // GEMM m-blocks (N_PAD/128)

typedef __bf16 bf16_t;
typedef bf16_t bf16x8 __attribute__((ext_vector_type(8)));
typedef float f32x4 __attribute__((ext_vector_type(4)));

__device__ __forceinline__ float bf2f(unsigned short u) {
    union { unsigned u32; float f; } x; x.u32 = ((unsigned)u) << 16; return x.f;
}
__device__ __forceinline__ unsigned short f2bf(float f) {
    union { float f; unsigned u; } x; x.f = f;
    unsigned r = (x.u + 0x7fffu + ((x.u >> 16) & 1u)) >> 16;
    return (unsigned short)r;
}

__device__ __forceinline__ void gl_lds16(const unsigned short* g, unsigned short* l) {
    __builtin_amdgcn_global_load_lds(
        (const __attribute__((address_space(1))) void*)g,
        (__attribute__((address_space(3))) void*)l, 16, 0, 0);
}

// MFMA-fragment-order packing for the B operand (weights), so a wave's fragment
// load is 64 lanes x 16B contiguous (1KB coalesced, L2-resident — no LDS needed).
// element (n,k) of W[K][256] -> frag index:
//   nb=n>>7 (128-col block), half=(n>>6)&1 (wave n-half), j=(n>>4)&3, lm=n&15
//   ks=k>>5, q=(k>>3)&3, e=k&7, lane=q*16+lm
//   off = (((nb*2+half)*4 + j)*(K/32) + ks)*512 + lane*8 + e
__device__ __forceinline__ size_t frag_off(int n, int k, int K) {
    int nb = n >> 7, half = (n >> 6) & 1, j = (n >> 4) & 3, lm = n & 15;
    int ks = k >> 5, q = (k >> 3) & 3, e = k & 7;
    return ((size_t)(((nb * 2 + half) * 4 + j) * (K >> 5) + ks)) * 512 + (q * 16 + lm) * 8 + e;
}

// ---- merged prep: weight hi/lo split into fragment order AND x f32->bf16 (6250 blocks)
__global__ void k_prep(const float* __restrict__ W_enc, const float* __restrict__ W1,
                       const float* __restrict__ W2, const float* __restrict__ x,
                       unsigned short* __restrict__ wench, unsigned short* __restrict__ wencl,
                       unsigned short* __restrict__ w1h, unsigned short* __restrict__ w1l,
                       unsigned short* __restrict__ w2h, unsigned short* __restrict__ w2l,
                       unsigned short* __restrict__ xb) {
    int idx = blockIdx.x * 256 + threadIdx.x;
    if (idx < 32768) {                       // W_enc [128][256], K=128
        float w = W_enc[idx];
        int k = idx >> 8, n = idx & 255;
        unsigned short h = f2bf(w), lo = f2bf(w - bf2f(h));
        size_t o = frag_off(n, k, 128);
        wench[o] = h; wencl[o] = lo;
    } else if (idx < 32768 + 196608) {       // W1 [3][256][256], K=256
        int j = idx - 32768;
        int l = j >> 16, r = j & 65535, k = r >> 8, n = r & 255;
        float w = W1[j];
        unsigned short h = f2bf(w), lo = f2bf(w - bf2f(h));
        size_t o = (size_t)l * 65536 + frag_off(n, k, 256);
        w1h[o] = h; w1l[o] = lo;
    } else if (idx < 32768 + 2 * 196608) {   // W2
        int j = idx - 32768 - 196608;
        int l = j >> 16, r = j & 65535, k = r >> 8, n = r & 255;
        float w = W2[j];
        unsigned short h = f2bf(w), lo = f2bf(w - bf2f(h));
        size_t o = (size_t)l * 65536 + frag_off(n, k, 256);
        w2h[o] = h; w2l[o] = lo;
    }
    if (idx < (N_NODES * F_INPUT) / 4) {     // x -> bf16, 4 at a time
        float4 v = reinterpret_cast<const float4*>(x)[idx];
        ushort4 o;
        o.x = f2bf(v.x); o.y = f2bf(v.y); o.z = f2bf(v.z); o.w = f2bf(v.w);
        reinterpret_cast<ushort4*>(xb)[idx] = o;
    }
}

// ---- per-block LDS histogram of dst (packed 2x16-bit, 2 node-range passes)
__global__ __launch_bounds__(512) void k_count(const int* __restrict__ dst,
                                               unsigned* __restrict__ slab) {
    __shared__ unsigned bins[16384];
    int b = blockIdx.x, t = threadIdx.x;
    int e0 = b * EPB, e1 = e0 + EPB;
    for (int pass = 0; pass < 2; ++pass) {
        int lo = pass << 15;
        int words = pass ? 8616 : 16384;
        for (int w = t; w < 16384; w += 512) bins[w] = 0;
        __syncthreads();
        for (int e = e0 + t; e < e1; e += 512) {
            int r = dst[e] - lo;
            if ((unsigned)r < 32768u)
                atomicAdd(&bins[r >> 1], 1u << ((r & 1) * 16));
        }
        __syncthreads();
        unsigned* out = slab + b * 25000 + (pass ? 16384 : 0);
        for (int w = t; w < words; w += 512) out[w] = bins[w];
        __syncthreads();
    }
}

// ---- reduce count slabs -> deg; graph boundaries from sorted batch -> gstart
__global__ void k_degred(const unsigned* __restrict__ slab, const int* __restrict__ batch,
                         int* __restrict__ deg, int* __restrict__ gstart) {
    int i = blockIdx.x * 256 + threadIdx.x;
    if (i < 25000) {
        unsigned s = 0;
#pragma unroll 8
        for (int b = 0; b < NBH; ++b) s += slab[b * 25000 + i];
        deg[2 * i] = s & 0xffff;
        deg[2 * i + 1] = s >> 16;
    }
    if (i < N_NODES) {
        int bt = batch[i];
        int pb = (i == 0) ? -1 : batch[i - 1];
        if (bt != pb)
            for (int g = pb + 1; g <= bt; ++g) gstart[g] = i;
        if (i == N_NODES - 1)
            for (int g = bt + 1; g <= NGRAPHS; ++g) gstart[g] = N_NODES;
    }
}

// ---- scan step 1: per-block inclusive scan of deg padded to multiple of 4
__global__ void k_scan1(const int* __restrict__ deg, int* __restrict__ rp1,
                        int* __restrict__ bsum) {
    __shared__ int s[256];
    int t = threadIdx.x, b = blockIdx.x, i = b * 256 + t;
    int d = (i < N_NODES) ? deg[i] : 0;
    int v = (d + 3) & ~3;
    s[t] = v; __syncthreads();
    for (int off = 1; off < 256; off <<= 1) {
        int x = (t >= off) ? s[t - off] : 0;
        __syncthreads(); s[t] += x; __syncthreads();
    }
    if (i < N_NODES) rp1[i] = s[t];
    if (t == 255) bsum[b] = s[255];
}

// ---- scan step 2: exclusive scan of block sums
__global__ void k_scan2(const int* __restrict__ bsum, int* __restrict__ boff, int nb) {
    __shared__ int s[256];
    int t = threadIdx.x;
    int v = (t < nb) ? bsum[t] : 0;
    s[t] = v; __syncthreads();
    for (int off = 1; off < 256; off <<= 1) {
        int x = (t >= off) ? s[t - off] : 0;
        __syncthreads(); s[t] += x; __syncthreads();
    }
    if (t < nb) boff[t] = s[t] - v;
}

// ---- scan step 3: add block offsets; finalize row_ptr[0]
__global__ void k_scan3(int* __restrict__ row_ptr, const int* __restrict__ boff) {
    int t = threadIdx.x, b = blockIdx.x, i = b * 256 + t;
    if (i < N_NODES) row_ptr[1 + i] += boff[b];
    if (i == 0) row_ptr[0] = 0;
}

// ---- per-(block,node) exclusive bases from count slabs; write pad edges (src = N_NODES)
__global__ void k_base(const unsigned* __restrict__ slab, const int* __restrict__ row_ptr,
                       int* __restrict__ base, int* __restrict__ csr_src) {
    int n = blockIdx.x * 256 + threadIdx.x;
    if (n >= N_NODES) return;
    int w = n >> 1, sh = (n & 1) * 16;
    int cur = row_ptr[n];
    int start = cur;
#pragma unroll 4
    for (int b = 0; b < NBH; ++b) {
        base[b * N_NODES + n] = cur;
        cur += (slab[b * 25000 + w] >> sh) & 0xffff;
    }
    int dg = cur - start;
    int padded = (dg + 3) & ~3;
    for (int p = dg; p < padded; ++p) csr_src[start + p] = N_NODES;
}

// ---- CSR fill with LDS cursors (no global atomics)
__global__ __launch_bounds__(512) void k_fill2(const int* __restrict__ src,
                                               const int* __restrict__ dst,
                                               const int* __restrict__ base,
                                               int* __restrict__ csr_src) {
    __shared__ unsigned bins[16384];
    int b = blockIdx.x, t = threadIdx.x;
    int e0 = b * EPB, e1 = e0 + EPB;
    for (int pass = 0; pass < 2; ++pass) {
        int lo = pass << 15;
        for (int w = t; w < 16384; w += 512) bins[w] = 0;
        __syncthreads();
        for (int e = e0 + t; e < e1; e += 512) {
            int d = dst[e];
            int r = d - lo;
            if ((unsigned)r < 32768u) {
                int sh = (r & 1) * 16;
                unsigned old = atomicAdd(&bins[r >> 1], 1u << sh);
                int local = (old >> sh) & 0xffff;
                csr_src[base[b * N_NODES + d] + local] = src[e];
            }
        }
        __syncthreads();
    }
}

// ---- aggregation, optionally fused with BN-affine+relu of the input
template <bool BN>
__global__ void k_agg(const unsigned short* __restrict__ zin, const int* __restrict__ row_ptr,
                      const int* __restrict__ csr_src,
                      const float* __restrict__ Ap, const float* __restrict__ Bp,
                      unsigned short* __restrict__ z0) {
    int wid = threadIdx.x >> 6, lane = threadIdx.x & 63;
    int half = lane >> 5, cl = lane & 31;
    int node = blockIdx.x * 8 + wid * 2 + half;   // grid = 6250
    const uint4* hp = reinterpret_cast<const uint4*>(zin);
    float Av[8], Bv[8];
    if (BN) {
        float4 a0 = *(const float4*)(Ap + cl * 8), a1 = *(const float4*)(Ap + cl * 8 + 4);
        float4 b0 = *(const float4*)(Bp + cl * 8), b1 = *(const float4*)(Bp + cl * 8 + 4);
        Av[0] = a0.x; Av[1] = a0.y; Av[2] = a0.z; Av[3] = a0.w;
        Av[4] = a1.x; Av[5] = a1.y; Av[6] = a1.z; Av[7] = a1.w;
        Bv[0] = b0.x; Bv[1] = b0.y; Bv[2] = b0.z; Bv[3] = b0.w;
        Bv[4] = b1.x; Bv[5] = b1.y; Bv[6] = b1.z; Bv[7] = b1.w;
    }
    uint4 own = hp[(size_t)node * 32 + cl];
    const unsigned short* op = (const unsigned short*)&own;
    float a[8];
#pragma unroll
    for (int i = 0; i < 8; ++i) {
        float z = bf2f(op[i]);
        a[i] = BN ? fmaxf(fmaf(Av[i], z, Bv[i]), 0.f) : z;
    }
    int e = row_ptr[node], end = row_ptr[node + 1];
    int4 nidx = {0, 0, 0, 0};
    if (e < end) nidx = *(const int4*)(csr_src + e);
    while (e < end) {
        int4 c = nidx;
        int en = e + 4;
        if (en < end) nidx = *(const int4*)(csr_src + en);
        uint4 v0 = hp[(size_t)c.x * 32 + cl];
        uint4 v1 = hp[(size_t)c.y * 32 + cl];
        uint4 v2 = hp[(size_t)c.z * 32 + cl];
        uint4 v3 = hp[(size_t)c.w * 32 + cl];
        e = en;
        const unsigned short* p0 = (const unsigned short*)&v0;
        const unsigned short* p1 = (const unsigned short*)&v1;
        const unsigned short* p2 = (const unsigned short*)&v2;
        const unsigned short* p3 = (const unsigned short*)&v3;
        if (BN) {
            float f0 = (c.x < N_NODES) ? 1.f : 0.f;
            float f1 = (c.y < N_NODES) ? 1.f : 0.f;
            float f2 = (c.z < N_NODES) ? 1.f : 0.f;
            float f3 = (c.w < N_NODES) ? 1.f : 0.f;
#pragma unroll
            for (int i = 0; i < 8; ++i) {
                float r0 = fmaxf(fmaf(Av[i], bf2f(p0[i]), Bv[i]), 0.f);
                float r1 = fmaxf(fmaf(Av[i], bf2f(p1[i]), Bv[i]), 0.f);
                float r2 = fmaxf(fmaf(Av[i], bf2f(p2[i]), Bv[i]), 0.f);
                float r3 = fmaxf(fmaf(Av[i], bf2f(p3[i]), Bv[i]), 0.f);
                a[i] += f0 * r0 + f1 * r1 + f2 * r2 + f3 * r3;
            }
        } else {
#pragma unroll
            for (int i = 0; i < 8; ++i)
                a[i] += (bf2f(p0[i]) + bf2f(p1[i])) + (bf2f(p2[i]) + bf2f(p3[i]));
        }
    }
    uint4 o;
    unsigned short* po = (unsigned short*)&o;
#pragma unroll
    for (int i = 0; i < 8; ++i) po[i] = f2bf(a[i]);
    reinterpret_cast<uint4*>(z0)[(size_t)node * 32 + cl] = o;
}

// ---- MFMA GEMM. A double-buffered in LDS (8KB x2, one barrier per k-step, DMA
// overlaps MFMA); B loaded directly from L2 as pre-packed COALESCED wave fragments
// (1KB contiguous per wave-load, no LDS). Optional fused column stats.
template <int K, bool RELU, bool STATS>
__global__ __launch_bounds__(256) void k_gemm(const unsigned short* __restrict__ A,
                                              const unsigned short* __restrict__ Whi,
                                              const unsigned short* __restrict__ Wlo,
                                              const float* __restrict__ bias,
                                              unsigned short* __restrict__ C,
                                              float* __restrict__ statsbuf, int M) {
    constexpr int KS = K / 32;
    __shared__ __align__(16) unsigned short As[2][128 * 32];   // 16 KB
    __shared__ float st[2][2][128];
    const int tid = threadIdx.x;
    const int m0 = blockIdx.x * 128;
    const int nb = blockIdx.y;
    const int wid = tid >> 6, lane = tid & 63;
    const int wm = (wid & 1) * 64, wn = (wid >> 1) * 64;
    const int lm = lane & 15, q = lane >> 4;

    // fragment stream base for this wave's n-half
    const unsigned short* fh = Whi + (size_t)((nb * 2 + (wid >> 1)) * 4) * KS * 512 + lane * 8;
    const unsigned short* fl = Wlo + (size_t)((nb * 2 + (wid >> 1)) * 4) * KS * 512 + lane * 8;

    auto stageA = [&](int ks, int buf) {
#pragma unroll
        for (int hf = 0; hf < 2; ++hf) {
            int r = (tid >> 2) + hf * 64;
            gl_lds16(A + (size_t)(m0 + r) * K + ks * 32 + (tid & 3) * 8,
                     &As[buf][r * 32 + (tid & 3) * 8]);
        }
    };

    f32x4 acc[4][4];
#pragma unroll
    for (int i = 0; i < 4; ++i)
#pragma unroll
        for (int j = 0; j < 4; ++j) acc[i][j] = (f32x4){0.f, 0.f, 0.f, 0.f};

    stageA(0, 0);
    int p = 0;
    for (int ks = 0; ks < KS; ++ks) {
        __syncthreads();                       // drains DMA(ks -> buf p)
        if (ks + 1 < KS) stageA(ks + 1, p ^ 1);  // overlaps with compute below
        bf16x8 bh[4], bl[4], af[4];
#pragma unroll
        for (int j = 0; j < 4; ++j) {
            bh[j] = *reinterpret_cast<const bf16x8*>(fh + (j * KS + ks) * 512);
            bl[j] = *reinterpret_cast<const bf16x8*>(fl + (j * KS + ks) * 512);
        }
#pragma unroll
        for (int i = 0; i < 4; ++i)
            af[i] = *reinterpret_cast<const bf16x8*>(&As[p][(wm + i * 16 + lm) * 32 + q * 8]);
#pragma unroll
        for (int i = 0; i < 4; ++i)
#pragma unroll
            for (int j = 0; j < 4; ++j) {
                acc[i][j] = __builtin_amdgcn_mfma_f32_16x16x32_bf16(af[i], bl[j], acc[i][j], 0, 0, 0);
                acc[i][j] = __builtin_amdgcn_mfma_f32_16x16x32_bf16(af[i], bh[j], acc[i][j], 0, 0, 0);
            }
        p ^= 1;
    }
    float bv[4];
#pragma unroll
    for (int j = 0; j < 4; ++j) bv[j] = bias[nb * 128 + wn + j * 16 + lm];
#pragma unroll
    for (int j = 0; j < 4; ++j) {
        int col = nb * 128 + wn + j * 16 + lm;
        float s = 0.f, s2 = 0.f;
#pragma unroll
        for (int i = 0; i < 4; ++i) {
            int row0 = m0 + wm + i * 16 + q * 4;
#pragma unroll
            for (int r = 0; r < 4; ++r) {
                int row = row0 + r;
                if (row < M) {
                    float v = acc[i][j][r] + bv[j];
                    if (STATS) { s += v; s2 = fmaf(v, v, s2); }
                    if (RELU) v = fmaxf(v, 0.f);
                    C[(size_t)row * DIM + col] = f2bf(v);
                }
            }
        }
        if (STATS) {
            s += __shfl_xor(s, 16); s += __shfl_xor(s, 32);
            s2 += __shfl_xor(s2, 16); s2 += __shfl_xor(s2, 32);
            if (q == 0) {
                st[0][wid & 1][wn + j * 16 + lm] = s;
                st[1][wid & 1][wn + j * 16 + lm] = s2;
            }
        }
    }
    if (STATS) {
        __syncthreads();
        if (tid < 256) {
            int sel = tid >> 7, cl2 = tid & 127;
            float v = st[sel][0][cl2] + st[sel][1][cl2];
            statsbuf[(size_t)(blockIdx.y * gridDim.x + blockIdx.x) * 256 + sel * 128 + cl2] = v;
        }
    }
}

// ---- stats reduce stage 1: 32 blocks x 512 thr, partial sums over slab chunks
__global__ __launch_bounds__(512) void k_statred1(const float* __restrict__ statsbuf,
                                                  float* __restrict__ spart) {
    int b = blockIdx.x, t = threadIdx.x;
    int is2 = t >> 8, c = t & 255;
    int by = c >> 7, cl = c & 127;
    int x0 = b * 13, x1 = x0 + 13;
    if (x1 > NGB) x1 = NGB;
    float s = 0.f;
    for (int bx = x0; bx < x1; ++bx)
        s += statsbuf[(size_t)(by * NGB + bx) * 256 + is2 * 128 + cl];
    spart[b * 512 + t] = s;
}

// ---- stats reduce stage 2: finalize BN affine  A=gamma*inv, B=beta-mean*A
__global__ void k_statred2(const float* __restrict__ spart, const float* __restrict__ gamma,
                           const float* __restrict__ beta, float* __restrict__ Ap,
                           float* __restrict__ Bp) {
    int c = threadIdx.x;   // 256
    float s = 0.f, s2 = 0.f;
#pragma unroll 8
    for (int b = 0; b < 32; ++b) {
        s += spart[b * 512 + c];
        s2 += spart[b * 512 + 256 + c];
    }
    float mean = s * (1.f / N_NODES);
    float var = s2 * (1.f / N_NODES) - mean * mean;
    float inv = rsqrtf(var + 1e-5f);
    float A = gamma[c] * inv;
    Ap[c] = A;
    Bp[c] = beta[c] - mean * A;
}

// ---- graph mean-pool of relu(A*z+B), unroll-4 independent accumulators
__global__ void k_pool(const unsigned short* __restrict__ z, const float* __restrict__ Ap,
                       const float* __restrict__ Bp, const int* __restrict__ gstart,
                       float* __restrict__ partl) {
    int g = blockIdx.x, sp = blockIdx.y, t = threadIdx.x;
    float A = Ap[t], B = Bp[t];
    int beg = gstart[g], c = gstart[g + 1] - beg;
    int chunk = (c + 3) >> 2;
    int r0 = beg + sp * chunk;
    int r1 = beg + c;
    int rlim = r0 + chunk;
    if (rlim < r1) r1 = rlim;
    float a0 = 0.f, a1 = 0.f, a2 = 0.f, a3 = 0.f;
    int r = r0;
    for (; r + 4 <= r1; r += 4) {
        float v0 = bf2f(z[(size_t)r * DIM + t]);
        float v1 = bf2f(z[(size_t)(r + 1) * DIM + t]);
        float v2 = bf2f(z[(size_t)(r + 2) * DIM + t]);
        float v3 = bf2f(z[(size_t)(r + 3) * DIM + t]);
        a0 += fmaxf(fmaf(A, v0, B), 0.f);
        a1 += fmaxf(fmaf(A, v1, B), 0.f);
        a2 += fmaxf(fmaf(A, v2, B), 0.f);
        a3 += fmaxf(fmaf(A, v3, B), 0.f);
    }
    for (; r < r1; ++r)
        a0 += fmaxf(fmaf(A, bf2f(z[(size_t)r * DIM + t]), B), 0.f);
    partl[(size_t)(g * 4 + sp) * 256 + t] = (a0 + a1) + (a2 + a3);
}

// ---- FC head: sums pool partials, divides by cnt, 2-layer MLP
__global__ __launch_bounds__(1024) void k_fc(const float* __restrict__ part,
                                             const int* __restrict__ gstart,
                                             const float* __restrict__ W1,
                                             const float* __restrict__ b1,
                                             const float* __restrict__ W2,
                                             const float* __restrict__ b2,
                                             float* __restrict__ out) {
    __shared__ float gs[DIM * NLAYERS];
    __shared__ float pt[8][128];
    __shared__ float red2[2];
    int g = blockIdx.x, t = threadIdx.x;
    float invc = 1.f / fmaxf((float)(gstart[g + 1] - gstart[g]), 1.f);
    for (int i = t; i < DIM * NLAYERS; i += 1024) {
        int l = i >> 8, c = i & 255;
        const float* pl = part + ((size_t)(l * NGRAPHS + g) * 4) * 256 + c;
        gs[i] = (pl[0] + pl[256] + pl[512] + pl[768]) * invc;
    }
    __syncthreads();
    int o = t & 127, kk = t >> 7;
    float acc = 0.f;
    const float* wp = W1 + (size_t)(kk * 96) * 128 + o;
#pragma unroll 4
    for (int k = 0; k < 96; ++k) acc = fmaf(gs[kk * 96 + k], wp[(size_t)k * 128], acc);
    pt[kk][o] = acc;
    __syncthreads();
    if (t < 128) {
        float v = b1[o];
#pragma unroll
        for (int p = 0; p < 8; ++p) v += pt[p][o];
        v = fmaxf(v, 0.f) * W2[o];
#pragma unroll
        for (int off = 32; off; off >>= 1) v += __shfl_down(v, off, 64);
        if ((t & 63) == 0) red2[t >> 6] = v;
    }
    __syncthreads();
    if (t == 0) out[g] = red2[0] + red2[1] + b2[0];
}

extern "C" void kernel_launch(void* const* d_in, const int* in_sizes, int n_in,
                              void* d_out, int out_size, void* d_ws, size_t ws_size,
                              hipStream_t stream) {
    const float* x = (const float*)d_in[0];
    const int* ei = (const int*)d_in[1];
    const int* batch = (const int*)d_in[2];
    const float* W_enc = (const float*)d_in[4];
    const float* b_enc = (const float*)d_in[5];
    const float* W1 = (const float*)d_in[6];
    const float* b1 = (const float*)d_in[7];
    const float* W2 = (const float*)d_in[8];
    const float* b2 = (const float*)d_in[9];
    const float* gamma = (const float*)d_in[10];
    const float* beta = (const float*)d_in[11];
    const float* Wfc1 = (const float*)d_in[12];
    const float* bfc1 = (const float*)d_in[13];
    const float* Wfc2 = (const float*)d_in[14];
    const float* bfc2 = (const float*)d_in[15];
    float* out = (float*)d_out;
    const int* srcp = ei;
    const int* dstp = ei + N_EDGES;

    // Workspace bump allocator (~110 MB)
    char* w = (char*)d_ws;
    auto alloc = [&](size_t b) -> char* {
        char* p = w;
        w += (b + 255) & ~(size_t)255;
        return p;
    };
    unsigned short* xb   = (unsigned short*)alloc((size_t)N_PAD * F_INPUT * 2);
    unsigned short* hbuf = (unsigned short*)alloc((size_t)N_PAD * DIM * 2);  // enc out; z0 for l>=1
    unsigned short* zA   = (unsigned short*)alloc((size_t)N_PAD * DIM * 2);  // z0@l0 / zbuf
    unsigned short* tbuf = (unsigned short*)alloc((size_t)N_PAD * DIM * 2);  // MLP mid; aliases basep
    unsigned short* wench = (unsigned short*)alloc(F_INPUT * DIM * 2);
    unsigned short* wencl = (unsigned short*)alloc(F_INPUT * DIM * 2);
    unsigned short* w1h = (unsigned short*)alloc((size_t)NLAYERS * DIM * DIM * 2);
    unsigned short* w1l = (unsigned short*)alloc((size_t)NLAYERS * DIM * DIM * 2);
    unsigned short* w2h = (unsigned short*)alloc((size_t)NLAYERS * DIM * DIM * 2);
    unsigned short* w2l = (unsigned short*)alloc((size_t)NLAYERS * DIM * DIM * 2);
    int* csr_src = (int*)alloc((size_t)(N_EDGES + 3 * N_NODES) * 4);
    int* row_ptr = (int*)alloc((size_t)(N_NODES + 1) * 4);
    unsigned* slab = (unsigned*)alloc((size_t)NBH * 25000 * 4);
    int* deg = (int*)alloc((size_t)N_NODES * 4);
    int* gstart = (int*)alloc((NGRAPHS + 1) * 4);
    int* bsum = (int*)alloc(256 * 4);
    int* boff = (int*)alloc(256 * 4);
    float* statsbuf = (float*)alloc((size_t)2 * NGB * 256 * 4);
    float* spart = (float*)alloc((size_t)32 * 512 * 4);
    float* Abn = (float*)alloc(256 * 4);
    float* Bbn = (float*)alloc(256 * 4);
    float* part = (float*)alloc((size_t)NLAYERS * NGRAPHS * 4 * 256 * 4);
    // basep (12.8 MB) aliases tbuf (25.6 MB): basep's lifetime ends before tbuf's first write
    int* basep = (int*)tbuf;

    // zero the dummy row (index N_NODES) of hbuf so pad edges add exact 0 in the plain agg
    hipMemsetAsync(hbuf + (size_t)N_NODES * DIM, 0, DIM * 2, stream);

    // prep: weights hi/lo fragment-packed + x->bf16 (6250 blocks: x-conversion bound)
    k_prep<<<6250, 256, 0, stream>>>(W_enc, W1, W2, x, wench, wencl, w1h, w1l, w2h, w2l, xb);

    // CSR build, atomic-free
    const int NB = (N_NODES + 255) / 256;  // 196
    k_count<<<NBH, 512, 0, stream>>>(dstp, slab);
    k_degred<<<NB, 256, 0, stream>>>(slab, batch, deg, gstart);
    k_scan1<<<NB, 256, 0, stream>>>(deg, row_ptr + 1, bsum);
    k_scan2<<<1, 256, 0, stream>>>(bsum, boff, NB);
    k_scan3<<<NB, 256, 0, stream>>>(row_ptr, boff);
    k_base<<<NB, 256, 0, stream>>>(slab, row_ptr, basep, csr_src);
    k_fill2<<<NBH, 512, 0, stream>>>(srcp, dstp, basep, csr_src);

    // encoder: h = x @ W_enc + b_enc
    dim3 ggrid(NGB, 2);
    k_gemm<F_INPUT, false, false><<<ggrid, 256, 0, stream>>>(xb, wench, wencl, b_enc, hbuf,
                                                             nullptr, N_NODES);

    dim3 pgrid(NGRAPHS, 4);
    for (int l = 0; l < NLAYERS; ++l) {
        const unsigned short* aggin = (l == 0) ? hbuf : zA;
        unsigned short* aggout = (l == 0) ? zA : hbuf;
        if (l == 0)
            k_agg<false><<<6250, 256, 0, stream>>>(aggin, row_ptr, csr_src, nullptr, nullptr, aggout);
        else
            k_agg<true><<<6250, 256, 0, stream>>>(aggin, row_ptr, csr_src, Abn, Bbn, aggout);
        k_gemm<DIM, true, false><<<ggrid, 256, 0, stream>>>(aggout, w1h + l * 65536, w1l + l * 65536,
                                                            b1 + l * DIM, tbuf, nullptr, N_NODES);
        k_gemm<DIM, false, true><<<ggrid, 256, 0, stream>>>(tbuf, w2h + l * 65536, w2l + l * 65536,
                                                            b2 + l * DIM, zA, statsbuf, N_NODES);
        k_statred1<<<32, 512, 0, stream>>>(statsbuf, spart);
        k_statred2<<<1, 256, 0, stream>>>(spart, gamma + l * DIM, beta + l * DIM, Abn, Bbn);
        k_pool<<<pgrid, 256, 0, stream>>>(zA, Abn, Bbn, gstart, part + (size_t)l * NGRAPHS * 4 * 256);
    }
    k_fc<<<NGRAPHS, 1024, 0, stream>>>(part, gstart, Wfc1, bfc1, Wfc2, bfc2, out);
}